// Round 13
// baseline (70.956 us; speedup 1.0000x reference)
//
#include <hip/hip_runtime.h>
#include <math.h>

#define NB   4
#define SEQN 512
#define SEQM 512
#define QS   256   // Q_SIZE == K_SIZE
#define HH   128   // H
#define DV   256   // D_V
#define BM   (NB * SEQM)   // 2048 global k rows

static constexpr float kPreScale = 2.8853900817779268f;  // 2*log2(e)
static constexpr float kLog2e    = 1.4426950408889634f;

#if __has_builtin(__builtin_amdgcn_exp2f)
__device__ __forceinline__ float fexp2(float x) { return __builtin_amdgcn_exp2f(x); }
#else
__device__ __forceinline__ float fexp2(float x) { return exp2f(x); }
#endif

#if __has_builtin(__builtin_amdgcn_rcpf)
__device__ __forceinline__ float frcp(float x) { return __builtin_amdgcn_rcpf(x); }
#else
__device__ __forceinline__ float frcp(float x) { return 1.0f / x; }
#endif

// Fused q/k projection + tanh precompute (unchanged).
// grid: 512 blocks, 512 threads. Block: 8 rows x 128 cols; thread: 2 rows.
__global__ __launch_bounds__(512) void proj_kernel(
    const float* __restrict__ query, const float* __restrict__ key,
    const float* __restrict__ Wq, const float* __restrict__ Wk,
    const float* __restrict__ wv,
    float* __restrict__ qt, float2* __restrict__ kt) {
  const int t = threadIdx.x;
  const int half = (NB * SEQN) / 8;            // 256
  const bool isK = blockIdx.x >= half;
  const int rb   = isK ? (blockIdx.x - half) : blockIdx.x;
  const float* __restrict__ in = isK ? key : query;
  const float* __restrict__ W  = isK ? Wk  : Wq;
  const int row0 = rb * 8;

  const int j  = t & 127;                                      // output column (h)
  const int r0 = __builtin_amdgcn_readfirstlane((t >> 7) * 2); // wave-uniform -> SGPR

  const float* __restrict__ x0p = in + (size_t)(row0 + r0 + 0) * QS;
  const float* __restrict__ x1p = in + (size_t)(row0 + r0 + 1) * QS;

  float a0 = 0.f, a1 = 0.f;
  for (int k0 = 0; k0 < QS; k0 += 4) {
    const float w0 = W[(k0 + 0) * HH + j];
    const float w1 = W[(k0 + 1) * HH + j];
    const float w2 = W[(k0 + 2) * HH + j];
    const float w3 = W[(k0 + 3) * HH + j];
    const float4 x0 = *reinterpret_cast<const float4*>(x0p + k0);  // s_load
    const float4 x1 = *reinterpret_cast<const float4*>(x1p + k0);
    a0 = fmaf(x0.x, w0, fmaf(x0.y, w1, fmaf(x0.z, w2, fmaf(x0.w, w3, a0))));
    a1 = fmaf(x1.x, w0, fmaf(x1.y, w1, fmaf(x1.z, w2, fmaf(x1.w, w3, a1))));
  }
  const float wvj = wv[j];
  float acc[2] = {a0, a1};
#pragma unroll
  for (int r = 0; r < 2; ++r) {
    const float e  = fexp2(acc[r] * kPreScale);          // e^{2x}
    const float rc = frcp(e + 1.0f);
    float A = fmaf(-2.0f, rc, 1.0f);                     // tanh(x)
    A = fminf(fmaxf(A, -0.99999988f), 0.99999988f);      // keep d = 1+AB > 0
    const int grow = row0 + r0 + r;
    if (isK) {
      kt[(size_t)j * BM + grow] = make_float2(A, wvj * A);
    } else {
      qt[(size_t)grow * (2 * HH) + j]      = A;
      qt[(size_t)grow * (2 * HH) + HH + j] = wvj * A;
    }
  }
}

// Fused scores + softmax + PV (R10 geometry; R13: q on the VMEM path).
// grid = NB * (SEQN/8) = 256 blocks, 1024 threads (16 waves), 48 KB LDS.
// Phase 1: thread (m = t&511, row-quad = t>>9) computes 4 scores via the
//          tanh-identity rational tree. k reg-double-buffered. q loads are
//          FORCED onto VMEM (opaque VGPR zero added to the base) so they
//          pipeline under counted vmcnt instead of serializing on
//          lgkmcnt(0) SMEM drains (the R7-R12 42%-VALUBusy plateau).
// Phase 2: in-wave full-row softmax.
// Phase 3: PV, 8 m-groups x float2 d-pairs; 4-buffer two-step LDS combine.
__global__ __launch_bounds__(1024) void fused_kernel(
    const float* __restrict__ qt, const float2* __restrict__ kt,
    const float* __restrict__ value, float* __restrict__ out) {
  __shared__ float sp[8][SEQM];        // 16 KB: scores then unnormalized p
  __shared__ float pvbuf[4][8][DV];    // 32 KB: PV partial buffers
  __shared__ float rsh[8];             // 1/rowsum

  const int t  = threadIdx.x;            // 0..1023
  const int b  = blockIdx.x >> 6;        // 4 batches x 64 tiles
  const int n0 = (blockIdx.x & 63) * 8;
  const int m  = t & 511;
  const int nq4 = __builtin_amdgcn_readfirstlane((t >> 9) * 4);

  // Opaque per-lane zero: compiler cannot prove uniformity -> q loads go to
  // the VMEM (global_load) path, in-order + counted vmcnt -> pipelineable.
  int lzero = 0;
  asm volatile("" : "+v"(lzero));

  const float* __restrict__ qb =
      qt + ((size_t)b * SEQN + n0 + nq4) * (2 * HH) + lzero;
  const float2* __restrict__ kb = kt + (size_t)b * SEQM + m;   // coalesced

  float N[4], D[4];
#pragma unroll
  for (int n = 0; n < 4; ++n) { N[n] = 0.f; D[n] = 1.f; }

  // register double-buffer: prefetch k chunk 0
  float2 fb[8];
#pragma unroll
  for (int jj = 0; jj < 8; ++jj) fb[jj] = kb[(size_t)jj * BM];

  for (int h0 = 0; h0 < HH; h0 += 8) {
    float kA[8], kW[8];
#pragma unroll
    for (int jj = 0; jj < 8; ++jj) { kA[jj] = fb[jj].x; kW[jj] = fb[jj].y; }
    if (h0 + 8 < HH) {
#pragma unroll
      for (int jj = 0; jj < 8; ++jj) fb[jj] = kb[(size_t)(h0 + 8 + jj) * BM];
    }
    // Batch ALL q loads of this chunk (4 rows x 4 vectors) -> 16 VMEM loads
    // in flight; compute gated by counted vmcnt, not a full drain.
    float4 qa0[4], qa1[4], qv0[4], qv1[4];
#pragma unroll
    for (int n = 0; n < 4; ++n) {
      const float* qr = qb + n * (2 * HH);
      qa0[n] = *reinterpret_cast<const float4*>(qr + h0);        // global_load
      qa1[n] = *reinterpret_cast<const float4*>(qr + h0 + 4);
      qv0[n] = *reinterpret_cast<const float4*>(qr + HH + h0);
      qv1[n] = *reinterpret_cast<const float4*>(qr + HH + h0 + 4);
    }
#pragma unroll
    for (int n = 0; n < 4; ++n) {
      const float4 a0 = qa0[n], a1 = qa1[n], v0 = qv0[n], v1 = qv1[n];
      // s_i = wv*(A+B), d_i = 1 + A*B  (d in (0,2))
      const float s0 = v0.x + kW[0], d0 = fmaf(a0.x, kA[0], 1.0f);
      const float s1 = v0.y + kW[1], d1 = fmaf(a0.y, kA[1], 1.0f);
      const float s2 = v0.z + kW[2], d2 = fmaf(a0.z, kA[2], 1.0f);
      const float s3 = v0.w + kW[3], d3 = fmaf(a0.w, kA[3], 1.0f);
      const float s4 = v1.x + kW[4], d4 = fmaf(a1.x, kA[4], 1.0f);
      const float s5 = v1.y + kW[5], d5 = fmaf(a1.y, kA[5], 1.0f);
      const float s6 = v1.z + kW[6], d6 = fmaf(a1.z, kA[6], 1.0f);
      const float s7 = v1.w + kW[7], d7 = fmaf(a1.w, kA[7], 1.0f);
      // pairwise rational tree: sum s_i/d_i -> t07/e07
      const float t01 = fmaf(s0, d1, s1 * d0), e01 = d0 * d1;
      const float t23 = fmaf(s2, d3, s3 * d2), e23 = d2 * d3;
      const float t45 = fmaf(s4, d5, s5 * d4), e45 = d4 * d5;
      const float t67 = fmaf(s6, d7, s7 * d6), e67 = d6 * d7;
      const float t03 = fmaf(t01, e23, t23 * e01), e03 = e01 * e23;
      const float t47 = fmaf(t45, e67, t67 * e45), e47 = e45 * e67;
      const float t07 = fmaf(t03, e47, t47 * e03), e07 = e03 * e47;
      N[n] = fmaf(N[n], e07, t07 * D[n]);
      D[n] *= e07;
    }
  }
#pragma unroll
  for (int n = 0; n < 4; ++n) sp[nq4 + n][m] = N[n] * frcp(D[n]);
  __syncthreads();

  // Phase 2: in-wave full-row softmax. wave w: row = w>>1, half = w&1.
  const int wave = t >> 6;
  const int lane = t & 63;
  const int row  = wave >> 1;
  const int hf   = wave & 1;
  float v[8];
  float mx = -1e30f;
#pragma unroll
  for (int i = 0; i < 8; ++i) {
    v[i] = sp[row][lane + 64 * i];     // full row, 8 vals/lane
    mx = fmaxf(mx, v[i]);
  }
#pragma unroll
  for (int off = 32; off > 0; off >>= 1) mx = fmaxf(mx, __shfl_xor(mx, off));
  float p[8];
  float sum = 0.f;
#pragma unroll
  for (int i = 0; i < 8; ++i) {
    p[i] = fexp2((v[i] - mx) * kLog2e);
    sum += p[i];
  }
#pragma unroll
  for (int off = 32; off > 0; off >>= 1) sum += __shfl_xor(sum, off);
  __syncthreads();                      // all row reads done before overwrite
#pragma unroll
  for (int i = 4 * hf; i < 4 * hf + 4; ++i) sp[row][lane + 64 * i] = p[i];
  if (hf == 0 && lane == 0) rsh[row] = frcp(sum);
  __syncthreads();

  // Phase 3: PV. mg = t>>7 (8 groups x 64 m), dp = (t&127)*2 (float2 d-pair).
  const float* __restrict__ vb = value + (size_t)b * SEQM * DV;
  const int dp = (t & 127) * 2;
  const int mg = t >> 7;
  float o[8][2];
#pragma unroll
  for (int n = 0; n < 8; ++n) { o[n][0] = 0.f; o[n][1] = 0.f; }
  const int mbeg = mg * 64;
  for (int mi = 0; mi < 64; mi += 4) {
    const int m0 = mbeg + mi;
    const float2 w0 = *reinterpret_cast<const float2*>(vb + (size_t)(m0 + 0) * DV + dp);
    const float2 w1 = *reinterpret_cast<const float2*>(vb + (size_t)(m0 + 1) * DV + dp);
    const float2 w2 = *reinterpret_cast<const float2*>(vb + (size_t)(m0 + 2) * DV + dp);
    const float2 w3 = *reinterpret_cast<const float2*>(vb + (size_t)(m0 + 3) * DV + dp);
#pragma unroll
    for (int n = 0; n < 8; ++n) {
      const float4 p4 = *reinterpret_cast<const float4*>(&sp[n][m0]);  // broadcast
      o[n][0] = fmaf(p4.x, w0.x, fmaf(p4.y, w1.x, fmaf(p4.z, w2.x, fmaf(p4.w, w3.x, o[n][0]))));
      o[n][1] = fmaf(p4.x, w0.y, fmaf(p4.y, w1.y, fmaf(p4.z, w2.y, fmaf(p4.w, w3.y, o[n][1]))));
    }
  }
  if (mg >= 4) {
#pragma unroll
    for (int n = 0; n < 8; ++n)
      *reinterpret_cast<float2*>(&pvbuf[mg - 4][n][dp]) = make_float2(o[n][0], o[n][1]);
  }
  __syncthreads();
  if (mg < 4) {
#pragma unroll
    for (int n = 0; n < 8; ++n) {
      float2 prev = *reinterpret_cast<const float2*>(&pvbuf[mg][n][dp]);
      prev.x += o[n][0]; prev.y += o[n][1];
      *reinterpret_cast<float2*>(&pvbuf[mg][n][dp]) = prev;
    }
  }
  __syncthreads();

  // Final: n = t>>7, d = t&127 (and d+128): 2 outputs/thread.
  {
    const int n = t >> 7;
    const int d = t & 127;
    const float rsn = rsh[n];
    float accA = 0.f, accB = 0.f;
#pragma unroll
    for (int g = 0; g < 4; ++g) {
      accA += pvbuf[g][n][d];
      accB += pvbuf[g][n][d + 128];
    }
    const size_t ob = ((size_t)b * SEQN + n0 + n) * DV;
    out[ob + d]       = accA * rsn;
    out[ob + d + 128] = accB * rsn;
  }
}

extern "C" void kernel_launch(void* const* d_in, const int* in_sizes, int n_in,
                              void* d_out, int out_size, void* d_ws, size_t ws_size,
                              hipStream_t stream) {
  const float* query = (const float*)d_in[0];   // (4,512,256)
  const float* key   = (const float*)d_in[1];   // (4,512,256)
  const float* value = (const float*)d_in[2];   // (4,512,256)
  const float* W_q   = (const float*)d_in[3];   // (256,128)
  const float* W_k   = (const float*)d_in[4];   // (256,128)
  const float* W_v   = (const float*)d_in[5];   // (128,)
  float* out = (float*)d_out;                   // (4,512,256) f32

  // qt parks in d_out (2 MB): fused block (b,n0) reads only its OWN 8 q-rows
  // in phase 1 and overwrites exactly those rows at the end -> no hazard.
  float*  qt = (float*)d_out;                   // (2048, 256) [A | wv*A]
  float2* kt = (float2*)d_ws;                   // (128, 2048) float2(A, wv*A), 2 MB

  proj_kernel<<<2 * (NB * SEQN) / 8, 512, 0, stream>>>(query, key, W_q, W_k, W_v, qt, kt);
  fused_kernel<<<NB * (SEQN / 8), 1024, 0, stream>>>(qt, kt, value, out);
}

// Round 14
// 47.808 us; speedup vs baseline: 1.4842x; 1.4842x over previous
//
#include <hip/hip_runtime.h>
#include <math.h>

#define NB   4
#define SEQN 512
#define SEQM 512
#define QS   256   // Q_SIZE == K_SIZE
#define HH   128   // H
#define DV   256   // D_V
#define BM   (NB * SEQM)   // 2048 global k rows

static constexpr float kPreScale = 2.8853900817779268f;  // 2*log2(e)
static constexpr float kLog2e    = 1.4426950408889634f;

#if __has_builtin(__builtin_amdgcn_exp2f)
__device__ __forceinline__ float fexp2(float x) { return __builtin_amdgcn_exp2f(x); }
#else
__device__ __forceinline__ float fexp2(float x) { return exp2f(x); }
#endif

#if __has_builtin(__builtin_amdgcn_rcpf)
__device__ __forceinline__ float frcp(float x) { return __builtin_amdgcn_rcpf(x); }
#else
__device__ __forceinline__ float frcp(float x) { return 1.0f / x; }
#endif

// Fused q/k projection + tanh precompute.
// grid: 512 blocks, 512 threads. Block: 8 rows x 128 cols; thread: 2 rows.
// Q output (row-major): qt[row][ A_0..A_127 | wv_0*A_0 .. wv_127*A_127 ]
// K output (transposed, PLAIN A): ktA[h][global_row] = A   (wv applied on the fly)
__global__ __launch_bounds__(512) void proj_kernel(
    const float* __restrict__ query, const float* __restrict__ key,
    const float* __restrict__ Wq, const float* __restrict__ Wk,
    const float* __restrict__ wv,
    float* __restrict__ qt, float* __restrict__ ktA) {
  const int t = threadIdx.x;
  const int half = (NB * SEQN) / 8;            // 256
  const bool isK = blockIdx.x >= half;
  const int rb   = isK ? (blockIdx.x - half) : blockIdx.x;
  const float* __restrict__ in = isK ? key : query;
  const float* __restrict__ W  = isK ? Wk  : Wq;
  const int row0 = rb * 8;

  const int j  = t & 127;                                      // output column (h)
  const int r0 = __builtin_amdgcn_readfirstlane((t >> 7) * 2); // wave-uniform -> SGPR

  const float* __restrict__ x0p = in + (size_t)(row0 + r0 + 0) * QS;
  const float* __restrict__ x1p = in + (size_t)(row0 + r0 + 1) * QS;

  float a0 = 0.f, a1 = 0.f;
  for (int k0 = 0; k0 < QS; k0 += 4) {
    const float w0 = W[(k0 + 0) * HH + j];
    const float w1 = W[(k0 + 1) * HH + j];
    const float w2 = W[(k0 + 2) * HH + j];
    const float w3 = W[(k0 + 3) * HH + j];
    const float4 x0 = *reinterpret_cast<const float4*>(x0p + k0);  // s_load
    const float4 x1 = *reinterpret_cast<const float4*>(x1p + k0);
    a0 = fmaf(x0.x, w0, fmaf(x0.y, w1, fmaf(x0.z, w2, fmaf(x0.w, w3, a0))));
    a1 = fmaf(x1.x, w0, fmaf(x1.y, w1, fmaf(x1.z, w2, fmaf(x1.w, w3, a1))));
  }
  const float wvj = wv[j];
  float acc[2] = {a0, a1};
#pragma unroll
  for (int r = 0; r < 2; ++r) {
    const float e  = fexp2(acc[r] * kPreScale);          // e^{2x}
    const float rc = frcp(e + 1.0f);
    float A = fmaf(-2.0f, rc, 1.0f);                     // tanh(x)
    A = fminf(fmaxf(A, -0.99999988f), 0.99999988f);      // keep d = 1+AB > 0
    const int grow = row0 + r0 + r;
    if (isK) {
      ktA[(size_t)j * BM + grow] = A;                    // plain A, coalesced
    } else {
      qt[(size_t)grow * (2 * HH) + j]      = A;
      qt[(size_t)grow * (2 * HH) + HH + j] = wvj * A;
    }
  }
}

// Fused scores + softmax + PV. R14: register tiling TN=2 x Mt=2 to HALVE the
// per-CU operand fetch count (the R7-R13 bottleneck: 256 SMEM fetches/chunk/CU
// saturated the scalar unit at VALUBusy~42%).
// grid = NB * (SEQN/8) = 256 blocks, 1024 threads (16 waves), 48 KB LDS.
// Thread (g = t>>8: row-pair n0+2g,+1; mslot = t&255: m = 2*mslot,+1)
// computes 4 scores. k = plain A (float2/h covers both m), u = wv*A_k on the
// fly (1 fma shared across rows). q via s_load (wave-uniform rows).
__global__ __launch_bounds__(1024) void fused_kernel(
    const float* __restrict__ qt, const float* __restrict__ ktA,
    const float* __restrict__ wv, const float* __restrict__ value,
    float* __restrict__ out) {
  __shared__ float sp[8][SEQM];        // 16 KB: scores then unnormalized p
  __shared__ float pvbuf[4][8][DV];    // 32 KB: PV partial buffers
  __shared__ float rsh[8];             // 1/rowsum

  const int t  = threadIdx.x;            // 0..1023
  const int b  = blockIdx.x >> 6;        // 4 batches x 64 tiles
  const int n0 = (blockIdx.x & 63) * 8;
  const int mslot = t & 255;
  const int m0 = 2 * mslot;
  // Wave-uniform row-pair base (waves never straddle 256-thread groups).
  const int g2 = __builtin_amdgcn_readfirstlane((t >> 8) * 2);

  const float* __restrict__ qb = qt + ((size_t)b * SEQN + n0 + g2) * (2 * HH);
  const float* __restrict__ kb = ktA + (size_t)b * SEQM + m0;   // coalesced float2

  float N00 = 0.f, N01 = 0.f, N10 = 0.f, N11 = 0.f;
  float D00 = 1.f, D01 = 1.f, D10 = 1.f, D11 = 1.f;

  // register double-buffer: prefetch k chunk 0 (8 h x 2 m)
  float2 fb[8];
#pragma unroll
  for (int jj = 0; jj < 8; ++jj) fb[jj] = *reinterpret_cast<const float2*>(kb + (size_t)jj * BM);

  for (int h0 = 0; h0 < HH; h0 += 8) {
    float bA0[8], bA1[8];
#pragma unroll
    for (int jj = 0; jj < 8; ++jj) { bA0[jj] = fb[jj].x; bA1[jj] = fb[jj].y; }
    if (h0 + 8 < HH) {
#pragma unroll
      for (int jj = 0; jj < 8; ++jj)
        fb[jj] = *reinterpret_cast<const float2*>(kb + (size_t)(h0 + 8 + jj) * BM);
    }
    // wv chunk: wave-uniform -> 2 s_load_dwordx4
    const float4 wva = *reinterpret_cast<const float4*>(wv + h0);
    const float4 wvb = *reinterpret_cast<const float4*>(wv + h0 + 4);
    // u = wv * A_k, shared across the 2 q-rows
    float u0[8], u1[8];
    u0[0] = wva.x * bA0[0]; u1[0] = wva.x * bA1[0];
    u0[1] = wva.y * bA0[1]; u1[1] = wva.y * bA1[1];
    u0[2] = wva.z * bA0[2]; u1[2] = wva.z * bA1[2];
    u0[3] = wva.w * bA0[3]; u1[3] = wva.w * bA1[3];
    u0[4] = wvb.x * bA0[4]; u1[4] = wvb.x * bA1[4];
    u0[5] = wvb.y * bA0[5]; u1[5] = wvb.y * bA1[5];
    u0[6] = wvb.z * bA0[6]; u1[6] = wvb.z * bA1[6];
    u0[7] = wvb.w * bA0[7]; u1[7] = wvb.w * bA1[7];
#pragma unroll
    for (int n = 0; n < 2; ++n) {
      const float* qr = qb + n * (2 * HH);
      const float4 a0 = *reinterpret_cast<const float4*>(qr + h0);           // s_load
      const float4 a1 = *reinterpret_cast<const float4*>(qr + h0 + 4);
      const float4 v0 = *reinterpret_cast<const float4*>(qr + HH + h0);
      const float4 v1 = *reinterpret_cast<const float4*>(qr + HH + h0 + 4);
#pragma unroll
      for (int mm = 0; mm < 2; ++mm) {
        const float* bA = (mm == 0) ? bA0 : bA1;
        const float* uu = (mm == 0) ? u0 : u1;
        const float s0 = v0.x + uu[0], d0 = fmaf(a0.x, bA[0], 1.0f);
        const float s1 = v0.y + uu[1], d1 = fmaf(a0.y, bA[1], 1.0f);
        const float s2 = v0.z + uu[2], d2 = fmaf(a0.z, bA[2], 1.0f);
        const float s3 = v0.w + uu[3], d3 = fmaf(a0.w, bA[3], 1.0f);
        const float s4 = v1.x + uu[4], d4 = fmaf(a1.x, bA[4], 1.0f);
        const float s5 = v1.y + uu[5], d5 = fmaf(a1.y, bA[5], 1.0f);
        const float s6 = v1.z + uu[6], d6 = fmaf(a1.z, bA[6], 1.0f);
        const float s7 = v1.w + uu[7], d7 = fmaf(a1.w, bA[7], 1.0f);
        // pairwise rational tree: sum s_i/d_i -> t07/e07
        const float t01 = fmaf(s0, d1, s1 * d0), e01 = d0 * d1;
        const float t23 = fmaf(s2, d3, s3 * d2), e23 = d2 * d3;
        const float t45 = fmaf(s4, d5, s5 * d4), e45 = d4 * d5;
        const float t67 = fmaf(s6, d7, s7 * d6), e67 = d6 * d7;
        const float t03 = fmaf(t01, e23, t23 * e01), e03 = e01 * e23;
        const float t47 = fmaf(t45, e67, t67 * e45), e47 = e45 * e67;
        const float t07 = fmaf(t03, e47, t47 * e03), e07 = e03 * e47;
        if (n == 0 && mm == 0) { N00 = fmaf(N00, e07, t07 * D00); D00 *= e07; }
        if (n == 0 && mm == 1) { N01 = fmaf(N01, e07, t07 * D01); D01 *= e07; }
        if (n == 1 && mm == 0) { N10 = fmaf(N10, e07, t07 * D10); D10 *= e07; }
        if (n == 1 && mm == 1) { N11 = fmaf(N11, e07, t07 * D11); D11 *= e07; }
      }
    }
  }
  sp[g2 + 0][m0 + 0] = N00 * frcp(D00);
  sp[g2 + 0][m0 + 1] = N01 * frcp(D01);
  sp[g2 + 1][m0 + 0] = N10 * frcp(D10);
  sp[g2 + 1][m0 + 1] = N11 * frcp(D11);
  __syncthreads();

  // Phase 2: in-wave full-row softmax. wave w: row = w>>1, half = w&1.
  const int wave = t >> 6;
  const int lane = t & 63;
  const int row  = wave >> 1;
  const int hf   = wave & 1;
  float v[8];
  float mx = -1e30f;
#pragma unroll
  for (int i = 0; i < 8; ++i) {
    v[i] = sp[row][lane + 64 * i];     // full row, 8 vals/lane
    mx = fmaxf(mx, v[i]);
  }
#pragma unroll
  for (int off = 32; off > 0; off >>= 1) mx = fmaxf(mx, __shfl_xor(mx, off));
  float p[8];
  float sum = 0.f;
#pragma unroll
  for (int i = 0; i < 8; ++i) {
    p[i] = fexp2((v[i] - mx) * kLog2e);
    sum += p[i];
  }
#pragma unroll
  for (int off = 32; off > 0; off >>= 1) sum += __shfl_xor(sum, off);
  __syncthreads();                      // all row reads done before overwrite
#pragma unroll
  for (int i = 4 * hf; i < 4 * hf + 4; ++i) sp[row][lane + 64 * i] = p[i];
  if (hf == 0 && lane == 0) rsh[row] = frcp(sum);
  __syncthreads();

  // Phase 3: PV. mg = t>>7 (8 groups x 64 m), dp = (t&127)*2 (float2 d-pair).
  const float* __restrict__ vb = value + (size_t)b * SEQM * DV;
  const int dp = (t & 127) * 2;
  const int mg = t >> 7;
  float o[8][2];
#pragma unroll
  for (int n = 0; n < 8; ++n) { o[n][0] = 0.f; o[n][1] = 0.f; }
  const int mbeg = mg * 64;
  for (int mi = 0; mi < 64; mi += 4) {
    const int mq = mbeg + mi;
    const float2 w0 = *reinterpret_cast<const float2*>(vb + (size_t)(mq + 0) * DV + dp);
    const float2 w1 = *reinterpret_cast<const float2*>(vb + (size_t)(mq + 1) * DV + dp);
    const float2 w2 = *reinterpret_cast<const float2*>(vb + (size_t)(mq + 2) * DV + dp);
    const float2 w3 = *reinterpret_cast<const float2*>(vb + (size_t)(mq + 3) * DV + dp);
#pragma unroll
    for (int n = 0; n < 8; ++n) {
      const float4 p4 = *reinterpret_cast<const float4*>(&sp[n][mq]);  // broadcast
      o[n][0] = fmaf(p4.x, w0.x, fmaf(p4.y, w1.x, fmaf(p4.z, w2.x, fmaf(p4.w, w3.x, o[n][0]))));
      o[n][1] = fmaf(p4.x, w0.y, fmaf(p4.y, w1.y, fmaf(p4.z, w2.y, fmaf(p4.w, w3.y, o[n][1]))));
    }
  }
  if (mg >= 4) {
#pragma unroll
    for (int n = 0; n < 8; ++n)
      *reinterpret_cast<float2*>(&pvbuf[mg - 4][n][dp]) = make_float2(o[n][0], o[n][1]);
  }
  __syncthreads();
  if (mg < 4) {
#pragma unroll
    for (int n = 0; n < 8; ++n) {
      float2 prev = *reinterpret_cast<const float2*>(&pvbuf[mg][n][dp]);
      prev.x += o[n][0]; prev.y += o[n][1];
      *reinterpret_cast<float2*>(&pvbuf[mg][n][dp]) = prev;
    }
  }
  __syncthreads();

  // Final: n = t>>7, d = t&127 (and d+128): 2 outputs/thread.
  {
    const int n = t >> 7;
    const int d = t & 127;
    const float rsn = rsh[n];
    float accA = 0.f, accB = 0.f;
#pragma unroll
    for (int g = 0; g < 4; ++g) {
      accA += pvbuf[g][n][d];
      accB += pvbuf[g][n][d + 128];
    }
    const size_t ob = ((size_t)b * SEQN + n0 + n) * DV;
    out[ob + d]       = accA * rsn;
    out[ob + d + 128] = accB * rsn;
  }
}

extern "C" void kernel_launch(void* const* d_in, const int* in_sizes, int n_in,
                              void* d_out, int out_size, void* d_ws, size_t ws_size,
                              hipStream_t stream) {
  const float* query = (const float*)d_in[0];   // (4,512,256)
  const float* key   = (const float*)d_in[1];   // (4,512,256)
  const float* value = (const float*)d_in[2];   // (4,512,256)
  const float* W_q   = (const float*)d_in[3];   // (256,128)
  const float* W_k   = (const float*)d_in[4];   // (256,128)
  const float* W_v   = (const float*)d_in[5];   // (128,)
  float* out = (float*)d_out;                   // (4,512,256) f32

  // qt parks in d_out (2 MB): fused block (b,n0) reads only its OWN 8 q-rows
  // in phase 1 and overwrites exactly those rows at the end -> no hazard.
  float* qt  = (float*)d_out;                   // (2048, 256) [A | wv*A]
  float* ktA = (float*)d_ws;                    // (128, 2048) plain A, 1 MB

  proj_kernel<<<2 * (NB * SEQN) / 8, 512, 0, stream>>>(query, key, W_q, W_k, W_v, qt, ktA);
  fused_kernel<<<NB * (SEQN / 8), 1024, 0, stream>>>(qt, ktA, W_v, value, out);
}

// Round 15
// 46.808 us; speedup vs baseline: 1.5159x; 1.0214x over previous
//
#include <hip/hip_runtime.h>
#include <math.h>

#define NB   4
#define SEQN 512
#define SEQM 512
#define QS   256   // Q_SIZE == K_SIZE
#define HH   128   // H
#define DV   256   // D_V
#define BM   (NB * SEQM)   // 2048 global k rows

static constexpr float kPreScale = 2.8853900817779268f;  // 2*log2(e)
static constexpr float kLog2e    = 1.4426950408889634f;

#if __has_builtin(__builtin_amdgcn_exp2f)
__device__ __forceinline__ float fexp2(float x) { return __builtin_amdgcn_exp2f(x); }
#else
__device__ __forceinline__ float fexp2(float x) { return exp2f(x); }
#endif

#if __has_builtin(__builtin_amdgcn_rcpf)
__device__ __forceinline__ float frcp(float x) { return __builtin_amdgcn_rcpf(x); }
#else
__device__ __forceinline__ float frcp(float x) { return 1.0f / x; }
#endif

// Fused q/k projection + tanh precompute (unchanged from R14).
// grid: 512 blocks, 512 threads. Block: 8 rows x 128 cols; thread: 2 rows.
// Q output (row-major): qt[row][ A_0..A_127 | wv_0*A_0 .. wv_127*A_127 ]
// K output (transposed, PLAIN A): ktA[h][global_row] = A
__global__ __launch_bounds__(512) void proj_kernel(
    const float* __restrict__ query, const float* __restrict__ key,
    const float* __restrict__ Wq, const float* __restrict__ Wk,
    const float* __restrict__ wv,
    float* __restrict__ qt, float* __restrict__ ktA) {
  const int t = threadIdx.x;
  const int half = (NB * SEQN) / 8;            // 256
  const bool isK = blockIdx.x >= half;
  const int rb   = isK ? (blockIdx.x - half) : blockIdx.x;
  const float* __restrict__ in = isK ? key : query;
  const float* __restrict__ W  = isK ? Wk  : Wq;
  const int row0 = rb * 8;

  const int j  = t & 127;                                      // output column (h)
  const int r0 = __builtin_amdgcn_readfirstlane((t >> 7) * 2); // wave-uniform -> SGPR

  const float* __restrict__ x0p = in + (size_t)(row0 + r0 + 0) * QS;
  const float* __restrict__ x1p = in + (size_t)(row0 + r0 + 1) * QS;

  float a0 = 0.f, a1 = 0.f;
  for (int k0 = 0; k0 < QS; k0 += 4) {
    const float w0 = W[(k0 + 0) * HH + j];
    const float w1 = W[(k0 + 1) * HH + j];
    const float w2 = W[(k0 + 2) * HH + j];
    const float w3 = W[(k0 + 3) * HH + j];
    const float4 x0 = *reinterpret_cast<const float4*>(x0p + k0);  // s_load
    const float4 x1 = *reinterpret_cast<const float4*>(x1p + k0);
    a0 = fmaf(x0.x, w0, fmaf(x0.y, w1, fmaf(x0.z, w2, fmaf(x0.w, w3, a0))));
    a1 = fmaf(x1.x, w0, fmaf(x1.y, w1, fmaf(x1.z, w2, fmaf(x1.w, w3, a1))));
  }
  const float wvj = wv[j];
  float acc[2] = {a0, a1};
#pragma unroll
  for (int r = 0; r < 2; ++r) {
    const float e  = fexp2(acc[r] * kPreScale);          // e^{2x}
    const float rc = frcp(e + 1.0f);
    float A = fmaf(-2.0f, rc, 1.0f);                     // tanh(x)
    A = fminf(fmaxf(A, -0.99999988f), 0.99999988f);      // keep d = 1+AB > 0
    const int grow = row0 + r0 + r;
    if (isK) {
      ktA[(size_t)j * BM + grow] = A;                    // plain A, coalesced
    } else {
      qt[(size_t)grow * (2 * HH) + j]      = A;
      qt[(size_t)grow * (2 * HH) + HH + j] = wvj * A;
    }
  }
}

// Fused scores + softmax + PV. R15: per-wave STAGGERED h-chunk order.
// R7-R14 diagnosis: one SMEM full-drain (lgkmcnt(0), SMEM is out-of-order so
// counted waits are impossible) per chunk costs ~300cyc vs ~352cyc compute;
// all waves ran in LOCKSTEP so drains aligned and the SIMD idled ~55%.
// Wave w now processes chunks (c+w)%16 -> on each SIMD the 4 waves' drains
// interleave with the other waves' compute.
// grid = NB * (SEQN/8) = 256 blocks, 1024 threads (16 waves), 48 KB LDS.
__global__ __launch_bounds__(1024) void fused_kernel(
    const float* __restrict__ qt, const float* __restrict__ ktA,
    const float* __restrict__ wv, const float* __restrict__ value,
    float* __restrict__ out) {
  __shared__ float sp[8][SEQM];        // 16 KB: scores then unnormalized p
  __shared__ float pvbuf[4][8][DV];    // 32 KB: PV partial buffers
  __shared__ float rsh[8];             // 1/rowsum

  const int t  = threadIdx.x;            // 0..1023
  const int b  = blockIdx.x >> 6;        // 4 batches x 64 tiles
  const int n0 = (blockIdx.x & 63) * 8;
  const int mslot = t & 255;
  const int m0 = 2 * mslot;
  // Wave-uniform row-pair base.
  const int g2   = __builtin_amdgcn_readfirstlane((t >> 8) * 2);
  // Wave id 0..15 -> chunk rotation offset (wave-uniform).
  const int woff = __builtin_amdgcn_readfirstlane(t >> 6);

  const float* __restrict__ qb = qt + ((size_t)b * SEQN + n0 + g2) * (2 * HH);
  const float* __restrict__ kb = ktA + (size_t)b * SEQM + m0;   // coalesced float2

  float N00 = 0.f, N01 = 0.f, N10 = 0.f, N11 = 0.f;
  float D00 = 1.f, D01 = 1.f, D10 = 1.f, D11 = 1.f;

  // register double-buffer: prefetch this wave's FIRST chunk (rotated)
  float2 fb[8];
  {
    const int hp = ((woff) & 15) * 8;
#pragma unroll
    for (int jj = 0; jj < 8; ++jj)
      fb[jj] = *reinterpret_cast<const float2*>(kb + (size_t)(hp + jj) * BM);
  }

  for (int c = 0; c < 16; ++c) {
    const int h0 = ((c + woff) & 15) * 8;        // current chunk (wave-uniform)
    float bA0[8], bA1[8];
#pragma unroll
    for (int jj = 0; jj < 8; ++jj) { bA0[jj] = fb[jj].x; bA1[jj] = fb[jj].y; }
    if (c + 1 < 16) {
      const int h1 = ((c + 1 + woff) & 15) * 8;  // next chunk
#pragma unroll
      for (int jj = 0; jj < 8; ++jj)
        fb[jj] = *reinterpret_cast<const float2*>(kb + (size_t)(h1 + jj) * BM);
    }
    // wv chunk: wave-uniform -> s_loads
    const float4 wva = *reinterpret_cast<const float4*>(wv + h0);
    const float4 wvb = *reinterpret_cast<const float4*>(wv + h0 + 4);
    // u = wv * A_k, shared across the 2 q-rows
    float u0[8], u1[8];
    u0[0] = wva.x * bA0[0]; u1[0] = wva.x * bA1[0];
    u0[1] = wva.y * bA0[1]; u1[1] = wva.y * bA1[1];
    u0[2] = wva.z * bA0[2]; u1[2] = wva.z * bA1[2];
    u0[3] = wva.w * bA0[3]; u1[3] = wva.w * bA1[3];
    u0[4] = wvb.x * bA0[4]; u1[4] = wvb.x * bA1[4];
    u0[5] = wvb.y * bA0[5]; u1[5] = wvb.y * bA1[5];
    u0[6] = wvb.z * bA0[6]; u1[6] = wvb.z * bA1[6];
    u0[7] = wvb.w * bA0[7]; u1[7] = wvb.w * bA1[7];
#pragma unroll
    for (int n = 0; n < 2; ++n) {
      const float* qr = qb + n * (2 * HH);
      const float4 a0 = *reinterpret_cast<const float4*>(qr + h0);           // s_load
      const float4 a1 = *reinterpret_cast<const float4*>(qr + h0 + 4);
      const float4 v0 = *reinterpret_cast<const float4*>(qr + HH + h0);
      const float4 v1 = *reinterpret_cast<const float4*>(qr + HH + h0 + 4);
#pragma unroll
      for (int mm = 0; mm < 2; ++mm) {
        const float* bA = (mm == 0) ? bA0 : bA1;
        const float* uu = (mm == 0) ? u0 : u1;
        const float s0 = v0.x + uu[0], d0 = fmaf(a0.x, bA[0], 1.0f);
        const float s1 = v0.y + uu[1], d1 = fmaf(a0.y, bA[1], 1.0f);
        const float s2 = v0.z + uu[2], d2 = fmaf(a0.z, bA[2], 1.0f);
        const float s3 = v0.w + uu[3], d3 = fmaf(a0.w, bA[3], 1.0f);
        const float s4 = v1.x + uu[4], d4 = fmaf(a1.x, bA[4], 1.0f);
        const float s5 = v1.y + uu[5], d5 = fmaf(a1.y, bA[5], 1.0f);
        const float s6 = v1.z + uu[6], d6 = fmaf(a1.z, bA[6], 1.0f);
        const float s7 = v1.w + uu[7], d7 = fmaf(a1.w, bA[7], 1.0f);
        // pairwise rational tree: sum s_i/d_i -> t07/e07
        const float t01 = fmaf(s0, d1, s1 * d0), e01 = d0 * d1;
        const float t23 = fmaf(s2, d3, s3 * d2), e23 = d2 * d3;
        const float t45 = fmaf(s4, d5, s5 * d4), e45 = d4 * d5;
        const float t67 = fmaf(s6, d7, s7 * d6), e67 = d6 * d7;
        const float t03 = fmaf(t01, e23, t23 * e01), e03 = e01 * e23;
        const float t47 = fmaf(t45, e67, t67 * e45), e47 = e45 * e67;
        const float t07 = fmaf(t03, e47, t47 * e03), e07 = e03 * e47;
        if (n == 0 && mm == 0) { N00 = fmaf(N00, e07, t07 * D00); D00 *= e07; }
        if (n == 0 && mm == 1) { N01 = fmaf(N01, e07, t07 * D01); D01 *= e07; }
        if (n == 1 && mm == 0) { N10 = fmaf(N10, e07, t07 * D10); D10 *= e07; }
        if (n == 1 && mm == 1) { N11 = fmaf(N11, e07, t07 * D11); D11 *= e07; }
      }
    }
  }
  sp[g2 + 0][m0 + 0] = N00 * frcp(D00);
  sp[g2 + 0][m0 + 1] = N01 * frcp(D01);
  sp[g2 + 1][m0 + 0] = N10 * frcp(D10);
  sp[g2 + 1][m0 + 1] = N11 * frcp(D11);
  __syncthreads();

  // Phase 2: in-wave full-row softmax. wave w: row = w>>1, half = w&1.
  const int wave = t >> 6;
  const int lane = t & 63;
  const int row  = wave >> 1;
  const int hf   = wave & 1;
  float v[8];
  float mx = -1e30f;
#pragma unroll
  for (int i = 0; i < 8; ++i) {
    v[i] = sp[row][lane + 64 * i];     // full row, 8 vals/lane
    mx = fmaxf(mx, v[i]);
  }
#pragma unroll
  for (int off = 32; off > 0; off >>= 1) mx = fmaxf(mx, __shfl_xor(mx, off));
  float p[8];
  float sum = 0.f;
#pragma unroll
  for (int i = 0; i < 8; ++i) {
    p[i] = fexp2((v[i] - mx) * kLog2e);
    sum += p[i];
  }
#pragma unroll
  for (int off = 32; off > 0; off >>= 1) sum += __shfl_xor(sum, off);
  __syncthreads();                      // all row reads done before overwrite
#pragma unroll
  for (int i = 4 * hf; i < 4 * hf + 4; ++i) sp[row][lane + 64 * i] = p[i];
  if (hf == 0 && lane == 0) rsh[row] = frcp(sum);
  __syncthreads();

  // Phase 3: PV. mg = t>>7 (8 groups x 64 m), dp = (t&127)*2 (float2 d-pair).
  const float* __restrict__ vb = value + (size_t)b * SEQM * DV;
  const int dp = (t & 127) * 2;
  const int mg = t >> 7;
  float o[8][2];
#pragma unroll
  for (int n = 0; n < 8; ++n) { o[n][0] = 0.f; o[n][1] = 0.f; }
  const int mbeg = mg * 64;
  for (int mi = 0; mi < 64; mi += 4) {
    const int mq = mbeg + mi;
    const float2 w0 = *reinterpret_cast<const float2*>(vb + (size_t)(mq + 0) * DV + dp);
    const float2 w1 = *reinterpret_cast<const float2*>(vb + (size_t)(mq + 1) * DV + dp);
    const float2 w2 = *reinterpret_cast<const float2*>(vb + (size_t)(mq + 2) * DV + dp);
    const float2 w3 = *reinterpret_cast<const float2*>(vb + (size_t)(mq + 3) * DV + dp);
#pragma unroll
    for (int n = 0; n < 8; ++n) {
      const float4 p4 = *reinterpret_cast<const float4*>(&sp[n][mq]);  // broadcast
      o[n][0] = fmaf(p4.x, w0.x, fmaf(p4.y, w1.x, fmaf(p4.z, w2.x, fmaf(p4.w, w3.x, o[n][0]))));
      o[n][1] = fmaf(p4.x, w0.y, fmaf(p4.y, w1.y, fmaf(p4.z, w2.y, fmaf(p4.w, w3.y, o[n][1]))));
    }
  }
  if (mg >= 4) {
#pragma unroll
    for (int n = 0; n < 8; ++n)
      *reinterpret_cast<float2*>(&pvbuf[mg - 4][n][dp]) = make_float2(o[n][0], o[n][1]);
  }
  __syncthreads();
  if (mg < 4) {
#pragma unroll
    for (int n = 0; n < 8; ++n) {
      float2 prev = *reinterpret_cast<const float2*>(&pvbuf[mg][n][dp]);
      prev.x += o[n][0]; prev.y += o[n][1];
      *reinterpret_cast<float2*>(&pvbuf[mg][n][dp]) = prev;
    }
  }
  __syncthreads();

  // Final: n = t>>7, d = t&127 (and d+128): 2 outputs/thread.
  {
    const int n = t >> 7;
    const int d = t & 127;
    const float rsn = rsh[n];
    float accA = 0.f, accB = 0.f;
#pragma unroll
    for (int g = 0; g < 4; ++g) {
      accA += pvbuf[g][n][d];
      accB += pvbuf[g][n][d + 128];
    }
    const size_t ob = ((size_t)b * SEQN + n0 + n) * DV;
    out[ob + d]       = accA * rsn;
    out[ob + d + 128] = accB * rsn;
  }
}

extern "C" void kernel_launch(void* const* d_in, const int* in_sizes, int n_in,
                              void* d_out, int out_size, void* d_ws, size_t ws_size,
                              hipStream_t stream) {
  const float* query = (const float*)d_in[0];   // (4,512,256)
  const float* key   = (const float*)d_in[1];   // (4,512,256)
  const float* value = (const float*)d_in[2];   // (4,512,256)
  const float* W_q   = (const float*)d_in[3];   // (256,128)
  const float* W_k   = (const float*)d_in[4];   // (256,128)
  const float* W_v   = (const float*)d_in[5];   // (128,)
  float* out = (float*)d_out;                   // (4,512,256) f32

  // qt parks in d_out (2 MB): fused block (b,n0) reads only its OWN 8 q-rows
  // in phase 1 and overwrites exactly those rows at the end -> no hazard.
  float* qt  = (float*)d_out;                   // (2048, 256) [A | wv*A]
  float* ktA = (float*)d_ws;                    // (128, 2048) plain A, 1 MB

  proj_kernel<<<2 * (NB * SEQN) / 8, 512, 0, stream>>>(query, key, W_q, W_k, W_v, qt, ktA);
  fused_kernel<<<NB * (SEQN / 8), 1024, 0, stream>>>(qt, ktA, W_v, value, out);
}